// Round 2
// baseline (4730.603 us; speedup 1.0000x reference)
//
#include <hip/hip_runtime.h>

#define N_NODES 100000
#define N_EDGES 600000
#define N_GRAPHS 2000
#define DIM 128
#define HIDDEN 256
#define N_CONV 4

// ---------------- degree / norm ----------------

__global__ __launch_bounds__(256) void k_deg_init(float* __restrict__ deg) {
    int i = blockIdx.x * 256 + threadIdx.x;
    if (i < N_NODES) deg[i] = 1.0f;  // self-loop
}

__global__ __launch_bounds__(256) void k_deg_edges(const int* __restrict__ ei, float* __restrict__ deg) {
    int e = blockIdx.x * 256 + threadIdx.x;
    if (e < N_EDGES) atomicAdd(&deg[ei[N_EDGES + e]], 1.0f);
}

__global__ __launch_bounds__(256) void k_rsqrt(float* __restrict__ deg) {
    int i = blockIdx.x * 256 + threadIdx.x;
    if (i < N_NODES) deg[i] = rsqrtf(deg[i]);
}

// ---------------- GEMM: C[N,128] = A[N,128] @ W[128,128] ----------------
// block: 256 threads, 64 rows. K split into 2 chunks of 64 to fit 64KB static LDS.
// thread (ty=t/16, tx=t%16): rows ty*4..+3, cols {tx*4..+3, 64+tx*4..+3}

__global__ __launch_bounds__(256) void k_gemm(const float* __restrict__ Ain,
                                              const float* __restrict__ W,
                                              float* __restrict__ Cout) {
    __shared__ float WL[64 * 128];   // 32 KB: rows kk..kk+63 of W
    __shared__ float AL[64][65];     // 16.6 KB, pad 65 -> conflict-free a reads

    int t = threadIdx.x;
    int row0 = blockIdx.x * 64;
    int ty = t >> 4;
    int tx = t & 15;

    const float4* A4 = (const float4*)Ain;
    const float4* W4 = (const float4*)W;
    float4* WL4 = (float4*)WL;

    float acc[4][8];
#pragma unroll
    for (int r = 0; r < 4; ++r)
#pragma unroll
        for (int c = 0; c < 8; ++c) acc[r][c] = 0.f;

    for (int kk = 0; kk < 128; kk += 64) {
        // stage W chunk: 64*128 floats = 2048 float4
#pragma unroll
        for (int i = 0; i < 8; ++i) {
            int f = i * 256 + t;
            WL4[f] = W4[kk * 32 + f];
        }
        // stage A chunk: 64 rows x 64 floats = 1024 float4
#pragma unroll
        for (int i = 0; i < 4; ++i) {
            int f = i * 256 + t;      // 0..1023
            int r = f >> 4;           // row in tile
            int c4 = f & 15;          // float4 within 64-float chunk
            float4 v = make_float4(0.f, 0.f, 0.f, 0.f);
            int row = row0 + r;
            if (row < N_NODES) v = A4[(size_t)row * 32 + (kk >> 2) + c4];
            AL[r][c4 * 4 + 0] = v.x;
            AL[r][c4 * 4 + 1] = v.y;
            AL[r][c4 * 4 + 2] = v.z;
            AL[r][c4 * 4 + 3] = v.w;
        }
        __syncthreads();

#pragma unroll 8
        for (int k = 0; k < 64; ++k) {
            float a[4];
#pragma unroll
            for (int r = 0; r < 4; ++r) a[r] = AL[ty * 4 + r][k];
            float4 b0 = *(const float4*)&WL[k * 128 + tx * 4];
            float4 b1 = *(const float4*)&WL[k * 128 + 64 + tx * 4];
#pragma unroll
            for (int r = 0; r < 4; ++r) {
                acc[r][0] += a[r] * b0.x; acc[r][1] += a[r] * b0.y;
                acc[r][2] += a[r] * b0.z; acc[r][3] += a[r] * b0.w;
                acc[r][4] += a[r] * b1.x; acc[r][5] += a[r] * b1.y;
                acc[r][6] += a[r] * b1.z; acc[r][7] += a[r] * b1.w;
            }
        }
        __syncthreads();
    }

    float4* C4 = (float4*)Cout;
#pragma unroll
    for (int r = 0; r < 4; ++r) {
        int row = row0 + ty * 4 + r;
        if (row < N_NODES) {
            C4[(size_t)row * 32 + tx]      = make_float4(acc[r][0], acc[r][1], acc[r][2], acc[r][3]);
            C4[(size_t)row * 32 + 16 + tx] = make_float4(acc[r][4], acc[r][5], acc[r][6], acc[r][7]);
        }
    }
}

// ---------------- aggregation ----------------

// A[i] = B[i] * dis[i]^2   (self-loop contribution; fully overwrites A)
__global__ __launch_bounds__(256) void k_agg_init(const float4* __restrict__ B4,
                                                  const float* __restrict__ dis,
                                                  float4* __restrict__ A4) {
    int idx = blockIdx.x * 256 + threadIdx.x;   // exactly N_NODES*32
    int node = idx >> 5;
    float d = dis[node];
    float n = d * d;
    float4 v = B4[idx];
    A4[idx] = make_float4(v.x * n, v.y * n, v.z * n, v.w * n);
}

// 32 lanes per edge, 1 float4 each, 4 atomic adds
__global__ __launch_bounds__(256) void k_scatter(const int* __restrict__ ei,
                                                 const float* __restrict__ dis,
                                                 const float4* __restrict__ B4,
                                                 float* __restrict__ A) {
    int t = threadIdx.x;
    int e = blockIdx.x * 8 + (t >> 5);          // 600000/8 = 75000 blocks exact
    int lane = t & 31;
    int src = ei[e];
    int dst = ei[N_EDGES + e];
    float nrm = dis[src] * dis[dst];
    float4 v = B4[src * 32 + lane];
    float* ap = A + (size_t)dst * 128 + lane * 4;
    atomicAdd(ap + 0, v.x * nrm);
    atomicAdd(ap + 1, v.y * nrm);
    atomicAdd(ap + 2, v.z * nrm);
    atomicAdd(ap + 3, v.w * nrm);
}

__global__ __launch_bounds__(256) void k_bias_relu(float4* __restrict__ A4,
                                                   const float* __restrict__ bias) {
    int idx = blockIdx.x * 256 + threadIdx.x;
    int c4 = idx & 31;
    float4 b = ((const float4*)bias)[c4];
    float4 v = A4[idx];
    v.x = fmaxf(v.x + b.x, 0.f);
    v.y = fmaxf(v.y + b.y, 0.f);
    v.z = fmaxf(v.z + b.z, 0.f);
    v.w = fmaxf(v.w + b.w, 0.f);
    A4[idx] = v;
}

// ---------------- pooling ----------------

__global__ __launch_bounds__(256) void k_count(const int* __restrict__ batch, float* __restrict__ cnt) {
    int i = blockIdx.x * 256 + threadIdx.x;
    if (i < N_NODES) atomicAdd(&cnt[batch[i]], 1.0f);
}

__global__ __launch_bounds__(256) void k_pool(const float4* __restrict__ A4,
                                              const int* __restrict__ batch,
                                              float* __restrict__ sums) {
    int idx = blockIdx.x * 256 + threadIdx.x;
    int node = idx >> 5;
    int c4 = idx & 31;
    int g = batch[node];
    float4 v = A4[idx];
    float* sp = sums + (size_t)g * 128 + c4 * 4;
    atomicAdd(sp + 0, v.x);
    atomicAdd(sp + 1, v.y);
    atomicAdd(sp + 2, v.z);
    atomicAdd(sp + 3, v.w);
}

// ---------------- MLP head: one block per graph ----------------

__global__ __launch_bounds__(256) void k_mlp(const float* __restrict__ sums,
                                             const float* __restrict__ cnt,
                                             const float* __restrict__ w1,
                                             const float* __restrict__ b1,
                                             const float* __restrict__ w2,
                                             const float* __restrict__ b2,
                                             float* __restrict__ out) {
    __shared__ float m[DIM];
    __shared__ float red[HIDDEN];
    int g = blockIdx.x;
    int t = threadIdx.x;
    float inv = 1.0f / fmaxf(cnt[g], 1.0f);
    if (t < DIM) m[t] = sums[g * DIM + t] * inv;
    __syncthreads();
    float h = b1[t];
    for (int c = 0; c < DIM; ++c) h += m[c] * w1[c * HIDDEN + t];
    red[t] = fmaxf(h, 0.f) * w2[t];
    __syncthreads();
    for (int s = HIDDEN / 2; s > 0; s >>= 1) {
        if (t < s) red[t] += red[t + s];
        __syncthreads();
    }
    if (t == 0) out[g] = red[0] + b2[0];
}

// ---------------- launch ----------------

extern "C" void kernel_launch(void* const* d_in, const int* in_sizes, int n_in,
                              void* d_out, int out_size, void* d_ws, size_t ws_size,
                              hipStream_t stream) {
    const float* x      = (const float*)d_in[0];
    const float* conv_w = (const float*)d_in[1];
    const float* conv_b = (const float*)d_in[2];
    const float* w1     = (const float*)d_in[3];
    const float* b1     = (const float*)d_in[4];
    const float* w2     = (const float*)d_in[5];
    const float* b2     = (const float*)d_in[6];
    const int*   ei     = (const int*)d_in[7];
    const int*   batch  = (const int*)d_in[8];
    float* out = (float*)d_out;

    char* ws = (char*)d_ws;
    size_t off = 0;
    auto alloc = [&](size_t bytes) {
        char* p = ws + off;
        off += (bytes + 255) & ~(size_t)255;
        return p;
    };
    float* A    = (float*)alloc((size_t)N_NODES * DIM * 4);   // 51.2 MB
    float* Bb   = (float*)alloc((size_t)N_NODES * DIM * 4);   // 51.2 MB
    float* dis  = (float*)alloc((size_t)N_NODES * 4);         // deg then rsqrt(deg)
    float* sums = (float*)alloc((size_t)N_GRAPHS * DIM * 4);
    float* cnt  = (float*)alloc((size_t)N_GRAPHS * 4);
    (void)ws_size; (void)in_sizes; (void)n_in; (void)out_size;

    hipMemsetAsync(sums, 0, (size_t)N_GRAPHS * DIM * 4, stream);
    hipMemsetAsync(cnt, 0, (size_t)N_GRAPHS * 4, stream);

    k_deg_init<<<(N_NODES + 255) / 256, 256, 0, stream>>>(dis);
    k_deg_edges<<<(N_EDGES + 255) / 256, 256, 0, stream>>>(ei, dis);
    k_rsqrt<<<(N_NODES + 255) / 256, 256, 0, stream>>>(dis);

    const float* cur = x;
    for (int L = 0; L < N_CONV; ++L) {
        k_gemm<<<(N_NODES + 63) / 64, 256, 0, stream>>>(cur, conv_w + L * DIM * DIM, Bb);
        k_agg_init<<<N_NODES * 32 / 256, 256, 0, stream>>>((const float4*)Bb, dis, (float4*)A);
        k_scatter<<<N_EDGES / 8, 256, 0, stream>>>(ei, dis, (const float4*)Bb, A);
        k_bias_relu<<<N_NODES * 32 / 256, 256, 0, stream>>>((float4*)A, conv_b + L * DIM);
        cur = A;
    }

    k_count<<<(N_NODES + 255) / 256, 256, 0, stream>>>(batch, cnt);
    k_pool<<<N_NODES * 32 / 256, 256, 0, stream>>>((const float4*)A, batch, sums);
    k_mlp<<<N_GRAPHS, 256, 0, stream>>>(sums, cnt, w1, b1, w2, b2, out);
}

// Round 3
// 838.632 us; speedup vs baseline: 5.6409x; 5.6409x over previous
//
#include <hip/hip_runtime.h>

#define N_NODES 100000
#define N_EDGES 600000
#define N_GRAPHS 2000
#define DIM 128
#define HIDDEN 256
#define N_CONV 4
#define NB_SCAN ((N_NODES + 255) / 256)   // 391

// ---------------- CSR build ----------------

__global__ __launch_bounds__(256) void k_hist(const int* __restrict__ ei, int* __restrict__ cnt) {
    int e = blockIdx.x * 256 + threadIdx.x;
    if (e < N_EDGES) atomicAdd(&cnt[ei[N_EDGES + e]], 1);
}

// dis = rsqrt(deg), deg = indeg + 1 (self-loop); always > 0
__global__ __launch_bounds__(256) void k_dis(const int* __restrict__ cnt, float* __restrict__ dis) {
    int i = blockIdx.x * 256 + threadIdx.x;
    if (i < N_NODES) dis[i] = rsqrtf(1.0f + (float)cnt[i]);
}

__global__ __launch_bounds__(256) void k_scan1(const int* __restrict__ cnt,
                                               int* __restrict__ rp,
                                               int* __restrict__ part) {
    __shared__ int s[256];
    int t = threadIdx.x;
    int i = blockIdx.x * 256 + t;
    int v = (i < N_NODES) ? cnt[i] : 0;
    s[t] = v;
    __syncthreads();
    for (int o = 1; o < 256; o <<= 1) {
        int x = (t >= o) ? s[t - o] : 0;
        __syncthreads();
        s[t] += x;
        __syncthreads();
    }
    if (i < N_NODES) rp[i] = s[t] - v;        // exclusive within block
    if (t == 255) part[blockIdx.x] = s[255];  // block total
}

__global__ __launch_bounds__(512) void k_scan2(int* __restrict__ part) {
    __shared__ int s[512];
    int t = threadIdx.x;
    int v = (t < NB_SCAN) ? part[t] : 0;
    s[t] = v;
    __syncthreads();
    for (int o = 1; o < 512; o <<= 1) {
        int x = (t >= o) ? s[t - o] : 0;
        __syncthreads();
        s[t] += x;
        __syncthreads();
    }
    if (t < NB_SCAN) part[t] = s[t] - v;      // exclusive block offsets
}

__global__ __launch_bounds__(256) void k_scan3(int* __restrict__ rp, const int* __restrict__ part) {
    int i = blockIdx.x * 256 + threadIdx.x;
    if (i < N_NODES) rp[i] += part[i >> 8];
    if (i == 0) rp[N_NODES] = N_EDGES;
}

__global__ __launch_bounds__(256) void k_fill(const int* __restrict__ ei,
                                              const int* __restrict__ rp,
                                              const float* __restrict__ dis,
                                              int* __restrict__ cursor,
                                              int* __restrict__ src_csr,
                                              float* __restrict__ norm_csr) {
    int e = blockIdx.x * 256 + threadIdx.x;
    if (e < N_EDGES) {
        int s = ei[e];
        int d = ei[N_EDGES + e];
        int pos = rp[d] + atomicAdd(&cursor[d], 1);
        src_csr[pos] = s;
        norm_csr[pos] = dis[s] * dis[d];
    }
}

// ---------------- GEMM: C[N,128] = A[N,128] @ W[128,128] ----------------

__global__ __launch_bounds__(256) void k_gemm(const float* __restrict__ Ain,
                                              const float* __restrict__ W,
                                              float* __restrict__ Cout) {
    __shared__ float WL[64 * 128];
    __shared__ float AL[64][65];

    int t = threadIdx.x;
    int row0 = blockIdx.x * 64;
    int ty = t >> 4;
    int tx = t & 15;

    const float4* A4 = (const float4*)Ain;
    const float4* W4 = (const float4*)W;
    float4* WL4 = (float4*)WL;

    float acc[4][8];
#pragma unroll
    for (int r = 0; r < 4; ++r)
#pragma unroll
        for (int c = 0; c < 8; ++c) acc[r][c] = 0.f;

    for (int kk = 0; kk < 128; kk += 64) {
#pragma unroll
        for (int i = 0; i < 8; ++i) {
            int f = i * 256 + t;
            WL4[f] = W4[kk * 32 + f];
        }
#pragma unroll
        for (int i = 0; i < 4; ++i) {
            int f = i * 256 + t;
            int r = f >> 4;
            int c4 = f & 15;
            float4 v = make_float4(0.f, 0.f, 0.f, 0.f);
            int row = row0 + r;
            if (row < N_NODES) v = A4[(size_t)row * 32 + (kk >> 2) + c4];
            AL[r][c4 * 4 + 0] = v.x;
            AL[r][c4 * 4 + 1] = v.y;
            AL[r][c4 * 4 + 2] = v.z;
            AL[r][c4 * 4 + 3] = v.w;
        }
        __syncthreads();

#pragma unroll 8
        for (int k = 0; k < 64; ++k) {
            float a[4];
#pragma unroll
            for (int r = 0; r < 4; ++r) a[r] = AL[ty * 4 + r][k];
            float4 b0 = *(const float4*)&WL[k * 128 + tx * 4];
            float4 b1 = *(const float4*)&WL[k * 128 + 64 + tx * 4];
#pragma unroll
            for (int r = 0; r < 4; ++r) {
                acc[r][0] += a[r] * b0.x; acc[r][1] += a[r] * b0.y;
                acc[r][2] += a[r] * b0.z; acc[r][3] += a[r] * b0.w;
                acc[r][4] += a[r] * b1.x; acc[r][5] += a[r] * b1.y;
                acc[r][6] += a[r] * b1.z; acc[r][7] += a[r] * b1.w;
            }
        }
        __syncthreads();
    }

    float4* C4 = (float4*)Cout;
#pragma unroll
    for (int r = 0; r < 4; ++r) {
        int row = row0 + ty * 4 + r;
        if (row < N_NODES) {
            C4[(size_t)row * 32 + tx]      = make_float4(acc[r][0], acc[r][1], acc[r][2], acc[r][3]);
            C4[(size_t)row * 32 + 16 + tx] = make_float4(acc[r][4], acc[r][5], acc[r][6], acc[r][7]);
        }
    }
}

// ---------------- pull aggregation + bias + relu (fused) ----------------
// 32-lane group per node; lane owns one float4 of the 128-dim row.

__global__ __launch_bounds__(256) void k_gather(const float4* __restrict__ B4,
                                                const int* __restrict__ rp,
                                                const int* __restrict__ src_csr,
                                                const float* __restrict__ norm_csr,
                                                const float* __restrict__ dis,
                                                const float* __restrict__ bias,
                                                float4* __restrict__ A4) {
    int t = threadIdx.x;
    int n = blockIdx.x * 8 + (t >> 5);      // 100000 / 8 = 12500 blocks exact
    int lane = t & 31;

    float dn = dis[n];
    float self_nrm = dn * dn;
    float4 v = B4[n * 32 + lane];
    float4 acc = make_float4(v.x * self_nrm, v.y * self_nrm, v.z * self_nrm, v.w * self_nrm);

    int beg = rp[n], end = rp[n + 1];
    for (int e = beg; e < end; ++e) {
        int s = src_csr[e];
        float nm = norm_csr[e];
        float4 u = B4[s * 32 + lane];
        acc.x += u.x * nm; acc.y += u.y * nm; acc.z += u.z * nm; acc.w += u.w * nm;
    }

    float4 b = ((const float4*)bias)[lane];
    acc.x = fmaxf(acc.x + b.x, 0.f);
    acc.y = fmaxf(acc.y + b.y, 0.f);
    acc.z = fmaxf(acc.z + b.z, 0.f);
    acc.w = fmaxf(acc.w + b.w, 0.f);
    A4[n * 32 + lane] = acc;
}

// ---------------- pooling ----------------

__global__ __launch_bounds__(256) void k_count(const int* __restrict__ batch, float* __restrict__ cnt) {
    int i = blockIdx.x * 256 + threadIdx.x;
    if (i < N_NODES) atomicAdd(&cnt[batch[i]], 1.0f);
}

__global__ __launch_bounds__(256) void k_pool(const float4* __restrict__ A4,
                                              const int* __restrict__ batch,
                                              float* __restrict__ sums) {
    int idx = blockIdx.x * 256 + threadIdx.x;
    int node = idx >> 5;
    int c4 = idx & 31;
    int g = batch[node];
    float4 v = A4[idx];
    float* sp = sums + (size_t)g * 128 + c4 * 4;
    atomicAdd(sp + 0, v.x);
    atomicAdd(sp + 1, v.y);
    atomicAdd(sp + 2, v.z);
    atomicAdd(sp + 3, v.w);
}

// ---------------- MLP head ----------------

__global__ __launch_bounds__(256) void k_mlp(const float* __restrict__ sums,
                                             const float* __restrict__ cnt,
                                             const float* __restrict__ w1,
                                             const float* __restrict__ b1,
                                             const float* __restrict__ w2,
                                             const float* __restrict__ b2,
                                             float* __restrict__ out) {
    __shared__ float m[DIM];
    __shared__ float red[HIDDEN];
    int g = blockIdx.x;
    int t = threadIdx.x;
    float inv = 1.0f / fmaxf(cnt[g], 1.0f);
    if (t < DIM) m[t] = sums[g * DIM + t] * inv;
    __syncthreads();
    float h = b1[t];
    for (int c = 0; c < DIM; ++c) h += m[c] * w1[c * HIDDEN + t];
    red[t] = fmaxf(h, 0.f) * w2[t];
    __syncthreads();
    for (int s = HIDDEN / 2; s > 0; s >>= 1) {
        if (t < s) red[t] += red[t + s];
        __syncthreads();
    }
    if (t == 0) out[g] = red[0] + b2[0];
}

// ---------------- launch ----------------

extern "C" void kernel_launch(void* const* d_in, const int* in_sizes, int n_in,
                              void* d_out, int out_size, void* d_ws, size_t ws_size,
                              hipStream_t stream) {
    const float* x      = (const float*)d_in[0];
    const float* conv_w = (const float*)d_in[1];
    const float* conv_b = (const float*)d_in[2];
    const float* w1     = (const float*)d_in[3];
    const float* b1     = (const float*)d_in[4];
    const float* w2     = (const float*)d_in[5];
    const float* b2     = (const float*)d_in[6];
    const int*   ei     = (const int*)d_in[7];
    const int*   batch  = (const int*)d_in[8];
    float* out = (float*)d_out;

    char* ws = (char*)d_ws;
    size_t off = 0;
    auto alloc = [&](size_t bytes) {
        char* p = ws + off;
        off += (bytes + 255) & ~(size_t)255;
        return p;
    };
    float* A        = (float*)alloc((size_t)N_NODES * DIM * 4);   // 51.2 MB
    float* Bb       = (float*)alloc((size_t)N_NODES * DIM * 4);   // 51.2 MB
    int*   cnt      = (int*)alloc((size_t)N_NODES * 4);           // hist, then reused as fill cursor
    float* dis      = (float*)alloc((size_t)N_NODES * 4);
    int*   rp       = (int*)alloc((size_t)(N_NODES + 1) * 4);
    int*   part     = (int*)alloc((size_t)NB_SCAN * 4);
    int*   src_csr  = (int*)alloc((size_t)N_EDGES * 4);
    float* norm_csr = (float*)alloc((size_t)N_EDGES * 4);
    float* sums     = (float*)alloc((size_t)N_GRAPHS * DIM * 4);
    float* cntg     = (float*)alloc((size_t)N_GRAPHS * 4);
    (void)ws_size; (void)in_sizes; (void)n_in; (void)out_size;

    // --- CSR build (once per call) ---
    hipMemsetAsync(cnt, 0, (size_t)N_NODES * 4, stream);
    k_hist<<<(N_EDGES + 255) / 256, 256, 0, stream>>>(ei, cnt);
    k_dis<<<(N_NODES + 255) / 256, 256, 0, stream>>>(cnt, dis);
    k_scan1<<<NB_SCAN, 256, 0, stream>>>(cnt, rp, part);
    k_scan2<<<1, 512, 0, stream>>>(part);
    k_scan3<<<NB_SCAN, 256, 0, stream>>>(rp, part);
    hipMemsetAsync(cnt, 0, (size_t)N_NODES * 4, stream);  // reuse as cursor
    k_fill<<<(N_EDGES + 255) / 256, 256, 0, stream>>>(ei, rp, dis, cnt, src_csr, norm_csr);

    // --- conv layers ---
    const float* cur = x;
    for (int L = 0; L < N_CONV; ++L) {
        k_gemm<<<(N_NODES + 63) / 64, 256, 0, stream>>>(cur, conv_w + L * DIM * DIM, Bb);
        k_gather<<<N_NODES / 8, 256, 0, stream>>>((const float4*)Bb, rp, src_csr, norm_csr,
                                                  dis, conv_b + L * DIM, (float4*)A);
        cur = A;
    }

    // --- pool + MLP ---
    hipMemsetAsync(sums, 0, (size_t)N_GRAPHS * DIM * 4, stream);
    hipMemsetAsync(cntg, 0, (size_t)N_GRAPHS * 4, stream);
    k_count<<<(N_NODES + 255) / 256, 256, 0, stream>>>(batch, cntg);
    k_pool<<<N_NODES * 32 / 256, 256, 0, stream>>>((const float4*)A, batch, sums);
    k_mlp<<<N_GRAPHS, 256, 0, stream>>>(sums, cntg, w1, b1, w2, b2, out);
}

// Round 5
// 606.235 us; speedup vs baseline: 7.8033x; 1.3833x over previous
//
#include <hip/hip_runtime.h>

#define N_NODES 100000
#define N_EDGES 600000
#define N_GRAPHS 2000
#define DIM 128
#define HIDDEN 256
#define N_CONV 4
#define NB_SCAN ((N_NODES + 255) / 256)   // 391

// ---------------- CSR build ----------------

__global__ __launch_bounds__(256) void k_hist(const int* __restrict__ ei, int* __restrict__ cnt) {
    int e = blockIdx.x * 256 + threadIdx.x;
    if (e < N_EDGES) atomicAdd(&cnt[ei[N_EDGES + e]], 1);
}

// dis = rsqrt(deg), deg = indeg + 1 (self-loop); always > 0
__global__ __launch_bounds__(256) void k_dis(const int* __restrict__ cnt, float* __restrict__ dis) {
    int i = blockIdx.x * 256 + threadIdx.x;
    if (i < N_NODES) dis[i] = rsqrtf(1.0f + (float)cnt[i]);
}

__global__ __launch_bounds__(256) void k_scan1(const int* __restrict__ cnt,
                                               int* __restrict__ rp,
                                               int* __restrict__ part) {
    __shared__ int s[256];
    int t = threadIdx.x;
    int i = blockIdx.x * 256 + t;
    int v = (i < N_NODES) ? cnt[i] : 0;
    s[t] = v;
    __syncthreads();
    for (int o = 1; o < 256; o <<= 1) {
        int x = (t >= o) ? s[t - o] : 0;
        __syncthreads();
        s[t] += x;
        __syncthreads();
    }
    if (i < N_NODES) rp[i] = s[t] - v;        // exclusive within block
    if (t == 255) part[blockIdx.x] = s[255];  // block total
}

__global__ __launch_bounds__(512) void k_scan2(int* __restrict__ part) {
    __shared__ int s[512];
    int t = threadIdx.x;
    int v = (t < NB_SCAN) ? part[t] : 0;
    s[t] = v;
    __syncthreads();
    for (int o = 1; o < 512; o <<= 1) {
        int x = (t >= o) ? s[t - o] : 0;
        __syncthreads();
        s[t] += x;
        __syncthreads();
    }
    if (t < NB_SCAN) part[t] = s[t] - v;      // exclusive block offsets
}

__global__ __launch_bounds__(256) void k_scan3(int* __restrict__ rp, const int* __restrict__ part) {
    int i = blockIdx.x * 256 + threadIdx.x;
    if (i < N_NODES) rp[i] += part[i >> 8];
    if (i == 0) rp[N_NODES] = N_EDGES;
}

__global__ __launch_bounds__(256) void k_fill(const int* __restrict__ ei,
                                              const int* __restrict__ rp,
                                              const float* __restrict__ dis,
                                              int* __restrict__ cursor,
                                              int* __restrict__ src_csr,
                                              float* __restrict__ norm_csr) {
    int e = blockIdx.x * 256 + threadIdx.x;
    if (e < N_EDGES) {
        int s = ei[e];
        int d = ei[N_EDGES + e];
        int pos = rp[d] + atomicAdd(&cursor[d], 1);
        src_csr[pos] = s;
        norm_csr[pos] = dis[s] * dis[d];
    }
}

// ---------------- graph row pointers from sorted batch ----------------

__global__ __launch_bounds__(256) void k_grp(const int* __restrict__ batch, int* __restrict__ grp) {
    int g = blockIdx.x * 256 + threadIdx.x;
    if (g > N_GRAPHS) return;
    if (g == N_GRAPHS) { grp[g] = N_NODES; return; }
    int lo = 0, hi = N_NODES;
    while (lo < hi) {
        int mid = (lo + hi) >> 1;
        if (batch[mid] < g) lo = mid + 1; else hi = mid;
    }
    grp[g] = lo;
}

// ---------------- GEMM: C[N,128] = A[N,128] @ W[128,128] ----------------

__global__ __launch_bounds__(256) void k_gemm(const float* __restrict__ Ain,
                                              const float* __restrict__ W,
                                              float* __restrict__ Cout) {
    __shared__ float WL[64 * 128];
    __shared__ float AL[64][65];

    int t = threadIdx.x;
    int row0 = blockIdx.x * 64;
    int ty = t >> 4;
    int tx = t & 15;

    const float4* A4 = (const float4*)Ain;
    const float4* W4 = (const float4*)W;
    float4* WL4 = (float4*)WL;

    float acc[4][8];
#pragma unroll
    for (int r = 0; r < 4; ++r)
#pragma unroll
        for (int c = 0; c < 8; ++c) acc[r][c] = 0.f;

    for (int kk = 0; kk < 128; kk += 64) {
#pragma unroll
        for (int i = 0; i < 8; ++i) {
            int f = i * 256 + t;
            WL4[f] = W4[kk * 32 + f];
        }
#pragma unroll
        for (int i = 0; i < 4; ++i) {
            int f = i * 256 + t;
            int r = f >> 4;
            int c4 = f & 15;
            float4 v = make_float4(0.f, 0.f, 0.f, 0.f);
            int row = row0 + r;
            if (row < N_NODES) v = A4[(size_t)row * 32 + (kk >> 2) + c4];
            AL[r][c4 * 4 + 0] = v.x;
            AL[r][c4 * 4 + 1] = v.y;
            AL[r][c4 * 4 + 2] = v.z;
            AL[r][c4 * 4 + 3] = v.w;
        }
        __syncthreads();

#pragma unroll 8
        for (int k = 0; k < 64; ++k) {
            float a[4];
#pragma unroll
            for (int r = 0; r < 4; ++r) a[r] = AL[ty * 4 + r][k];
            float4 b0 = *(const float4*)&WL[k * 128 + tx * 4];
            float4 b1 = *(const float4*)&WL[k * 128 + 64 + tx * 4];
#pragma unroll
            for (int r = 0; r < 4; ++r) {
                acc[r][0] += a[r] * b0.x; acc[r][1] += a[r] * b0.y;
                acc[r][2] += a[r] * b0.z; acc[r][3] += a[r] * b0.w;
                acc[r][4] += a[r] * b1.x; acc[r][5] += a[r] * b1.y;
                acc[r][6] += a[r] * b1.z; acc[r][7] += a[r] * b1.w;
            }
        }
        __syncthreads();
    }

    float4* C4 = (float4*)Cout;
#pragma unroll
    for (int r = 0; r < 4; ++r) {
        int row = row0 + ty * 4 + r;
        if (row < N_NODES) {
            C4[(size_t)row * 32 + tx]      = make_float4(acc[r][0], acc[r][1], acc[r][2], acc[r][3]);
            C4[(size_t)row * 32 + 16 + tx] = make_float4(acc[r][4], acc[r][5], acc[r][6], acc[r][7]);
        }
    }
}

// ---------------- pull aggregation + bias + relu (fused) ----------------
// 32-lane group per node; lane owns one float4 of the 128-dim row.

__global__ __launch_bounds__(256) void k_gather(const float4* __restrict__ B4,
                                                const int* __restrict__ rp,
                                                const int* __restrict__ src_csr,
                                                const float* __restrict__ norm_csr,
                                                const float* __restrict__ dis,
                                                const float* __restrict__ bias,
                                                float4* __restrict__ A4) {
    int t = threadIdx.x;
    int n = blockIdx.x * 8 + (t >> 5);      // 100000 / 8 = 12500 blocks exact
    int lane = t & 31;

    float dn = dis[n];
    float self_nrm = dn * dn;
    float4 v = B4[n * 32 + lane];
    float4 acc = make_float4(v.x * self_nrm, v.y * self_nrm, v.z * self_nrm, v.w * self_nrm);

    int beg = rp[n], end = rp[n + 1];
    int e = beg;
    for (; e + 1 < end; e += 2) {
        int s0 = src_csr[e];
        int s1 = src_csr[e + 1];
        float nm0 = norm_csr[e];
        float nm1 = norm_csr[e + 1];
        float4 u0 = B4[s0 * 32 + lane];
        float4 u1 = B4[s1 * 32 + lane];
        acc.x += u0.x * nm0; acc.y += u0.y * nm0; acc.z += u0.z * nm0; acc.w += u0.w * nm0;
        acc.x += u1.x * nm1; acc.y += u1.y * nm1; acc.z += u1.z * nm1; acc.w += u1.w * nm1;
    }
    if (e < end) {
        int s0 = src_csr[e];
        float nm0 = norm_csr[e];
        float4 u0 = B4[s0 * 32 + lane];
        acc.x += u0.x * nm0; acc.y += u0.y * nm0; acc.z += u0.z * nm0; acc.w += u0.w * nm0;
    }

    float4 b = ((const float4*)bias)[lane];
    acc.x = fmaxf(acc.x + b.x, 0.f);
    acc.y = fmaxf(acc.y + b.y, 0.f);
    acc.z = fmaxf(acc.z + b.z, 0.f);
    acc.w = fmaxf(acc.w + b.w, 0.f);
    A4[n * 32 + lane] = acc;
}

// ---------------- segmented pooling (batch is sorted -> contiguous ranges) ----------------
// one block per graph; 8 node-slots x 32 dim-lanes; fuses mean division.

__global__ __launch_bounds__(256) void k_pool_seg(const float4* __restrict__ A4,
                                                  const int* __restrict__ grp,
                                                  float4* __restrict__ means4) {
    __shared__ float4 s[256];
    int g = blockIdx.x;
    int t = threadIdx.x;
    int lane = t & 31;
    int slot = t >> 5;
    int beg = grp[g], end = grp[g + 1];

    float4 acc = make_float4(0.f, 0.f, 0.f, 0.f);
    for (int n = beg + slot; n < end; n += 8) {
        float4 v = A4[(size_t)n * 32 + lane];
        acc.x += v.x; acc.y += v.y; acc.z += v.z; acc.w += v.w;
    }
    s[t] = acc;
    __syncthreads();
    if (t < 32) {
        float4 a = s[t];
#pragma unroll
        for (int i = 1; i < 8; ++i) {
            float4 b = s[t + i * 32];
            a.x += b.x; a.y += b.y; a.z += b.z; a.w += b.w;
        }
        float inv = (end > beg) ? 1.0f / (float)(end - beg) : 0.0f;
        means4[g * 32 + t] = make_float4(a.x * inv, a.y * inv, a.z * inv, a.w * inv);
    }
}

// ---------------- MLP head ----------------

__global__ __launch_bounds__(256) void k_mlp(const float* __restrict__ means,
                                             const float* __restrict__ w1,
                                             const float* __restrict__ b1,
                                             const float* __restrict__ w2,
                                             const float* __restrict__ b2,
                                             float* __restrict__ out) {
    __shared__ float m[DIM];
    __shared__ float red[HIDDEN];
    int g = blockIdx.x;
    int t = threadIdx.x;
    if (t < DIM) m[t] = means[g * DIM + t];
    __syncthreads();
    float h = b1[t];
    for (int c = 0; c < DIM; ++c) h += m[c] * w1[c * HIDDEN + t];
    red[t] = fmaxf(h, 0.f) * w2[t];
    __syncthreads();
    for (int s = HIDDEN / 2; s > 0; s >>= 1) {
        if (t < s) red[t] += red[t + s];
        __syncthreads();
    }
    if (t == 0) out[g] = red[0] + b2[0];
}

// ---------------- launch ----------------

extern "C" void kernel_launch(void* const* d_in, const int* in_sizes, int n_in,
                              void* d_out, int out_size, void* d_ws, size_t ws_size,
                              hipStream_t stream) {
    const float* x      = (const float*)d_in[0];
    const float* conv_w = (const float*)d_in[1];
    const float* conv_b = (const float*)d_in[2];
    const float* w1     = (const float*)d_in[3];
    const float* b1     = (const float*)d_in[4];
    const float* w2     = (const float*)d_in[5];
    const float* b2     = (const float*)d_in[6];
    const int*   ei     = (const int*)d_in[7];
    const int*   batch  = (const int*)d_in[8];
    float* out = (float*)d_out;

    char* ws = (char*)d_ws;
    size_t off = 0;
    auto alloc = [&](size_t bytes) {
        char* p = ws + off;
        off += (bytes + 255) & ~(size_t)255;
        return p;
    };
    float* A        = (float*)alloc((size_t)N_NODES * DIM * 4);   // 51.2 MB
    float* Bb       = (float*)alloc((size_t)N_NODES * DIM * 4);   // 51.2 MB
    int*   cnt      = (int*)alloc((size_t)N_NODES * 4);           // hist, then reused as fill cursor
    float* dis      = (float*)alloc((size_t)N_NODES * 4);
    int*   rp       = (int*)alloc((size_t)(N_NODES + 1) * 4);
    int*   part     = (int*)alloc((size_t)NB_SCAN * 4);
    int*   src_csr  = (int*)alloc((size_t)N_EDGES * 4);
    float* norm_csr = (float*)alloc((size_t)N_EDGES * 4);
    int*   grp      = (int*)alloc((size_t)(N_GRAPHS + 1) * 4);
    float* means    = (float*)alloc((size_t)N_GRAPHS * DIM * 4);
    (void)ws_size; (void)in_sizes; (void)n_in; (void)out_size;

    // --- CSR build (once per call) ---
    hipMemsetAsync(cnt, 0, (size_t)N_NODES * 4, stream);
    k_hist<<<(N_EDGES + 255) / 256, 256, 0, stream>>>(ei, cnt);
    k_dis<<<(N_NODES + 255) / 256, 256, 0, stream>>>(cnt, dis);
    k_scan1<<<NB_SCAN, 256, 0, stream>>>(cnt, rp, part);
    k_scan2<<<1, 512, 0, stream>>>(part);
    k_scan3<<<NB_SCAN, 256, 0, stream>>>(rp, part);
    hipMemsetAsync(cnt, 0, (size_t)N_NODES * 4, stream);  // reuse as cursor
    k_fill<<<(N_EDGES + 255) / 256, 256, 0, stream>>>(ei, rp, dis, cnt, src_csr, norm_csr);
    k_grp<<<(N_GRAPHS + 256) / 256, 256, 0, stream>>>(batch, grp);

    // --- conv layers ---
    const float* cur = x;
    for (int L = 0; L < N_CONV; ++L) {
        k_gemm<<<(N_NODES + 63) / 64, 256, 0, stream>>>(cur, conv_w + L * DIM * DIM, Bb);
        k_gather<<<N_NODES / 8, 256, 0, stream>>>((const float4*)Bb, rp, src_csr, norm_csr,
                                                  dis, conv_b + L * DIM, (float4*)A);
        cur = A;
    }

    // --- pool + MLP ---
    k_pool_seg<<<N_GRAPHS, 256, 0, stream>>>((const float4*)A, grp, (float4*)means);
    k_mlp<<<N_GRAPHS, 256, 0, stream>>>(means, w1, b1, w2, b2, out);
}

// Round 6
// 506.029 us; speedup vs baseline: 9.3485x; 1.1980x over previous
//
#include <hip/hip_runtime.h>

#define N_NODES 100000
#define N_EDGES 600000
#define N_GRAPHS 2000
#define DIM 128
#define HIDDEN 256
#define N_CONV 4
#define NB_SCAN ((N_NODES + 255) / 256)   // 391

typedef short s16x8 __attribute__((ext_vector_type(8)));
typedef float f32x4 __attribute__((ext_vector_type(4)));

// ---------------- CSR build ----------------

__global__ __launch_bounds__(256) void k_hist(const int* __restrict__ ei, int* __restrict__ cnt) {
    int e = blockIdx.x * 256 + threadIdx.x;
    if (e < N_EDGES) atomicAdd(&cnt[ei[N_EDGES + e]], 1);
}

__global__ __launch_bounds__(256) void k_dis(const int* __restrict__ cnt, float* __restrict__ dis) {
    int i = blockIdx.x * 256 + threadIdx.x;
    if (i < N_NODES) dis[i] = rsqrtf(1.0f + (float)cnt[i]);
}

__global__ __launch_bounds__(256) void k_scan1(const int* __restrict__ cnt,
                                               int* __restrict__ rp,
                                               int* __restrict__ part) {
    __shared__ int s[256];
    int t = threadIdx.x;
    int i = blockIdx.x * 256 + t;
    int v = (i < N_NODES) ? cnt[i] : 0;
    s[t] = v;
    __syncthreads();
    for (int o = 1; o < 256; o <<= 1) {
        int x = (t >= o) ? s[t - o] : 0;
        __syncthreads();
        s[t] += x;
        __syncthreads();
    }
    if (i < N_NODES) rp[i] = s[t] - v;
    if (t == 255) part[blockIdx.x] = s[255];
}

__global__ __launch_bounds__(512) void k_scan2(int* __restrict__ part) {
    __shared__ int s[512];
    int t = threadIdx.x;
    int v = (t < NB_SCAN) ? part[t] : 0;
    s[t] = v;
    __syncthreads();
    for (int o = 1; o < 512; o <<= 1) {
        int x = (t >= o) ? s[t - o] : 0;
        __syncthreads();
        s[t] += x;
        __syncthreads();
    }
    if (t < NB_SCAN) part[t] = s[t] - v;
}

__global__ __launch_bounds__(256) void k_scan3(int* __restrict__ rp, const int* __restrict__ part) {
    int i = blockIdx.x * 256 + threadIdx.x;
    if (i < N_NODES) rp[i] += part[i >> 8];
    if (i == 0) rp[N_NODES] = N_EDGES;
}

__global__ __launch_bounds__(256) void k_fill(const int* __restrict__ ei,
                                              const int* __restrict__ rp,
                                              const float* __restrict__ dis,
                                              int* __restrict__ cursor,
                                              int* __restrict__ src_csr,
                                              float* __restrict__ norm_csr) {
    int e = blockIdx.x * 256 + threadIdx.x;
    if (e < N_EDGES) {
        int s = ei[e];
        int d = ei[N_EDGES + e];
        int pos = rp[d] + atomicAdd(&cursor[d], 1);
        src_csr[pos] = s;
        norm_csr[pos] = dis[s] * dis[d];
    }
}

// ---------------- graph row pointers from sorted batch ----------------

__global__ __launch_bounds__(256) void k_grp(const int* __restrict__ batch, int* __restrict__ grp) {
    int g = blockIdx.x * 256 + threadIdx.x;
    if (g > N_GRAPHS) return;
    if (g == N_GRAPHS) { grp[g] = N_NODES; return; }
    int lo = 0, hi = N_NODES;
    while (lo < hi) {
        int mid = (lo + hi) >> 1;
        if (batch[mid] < g) lo = mid + 1; else hi = mid;
    }
    grp[g] = lo;
}

// ---------------- W split: WhT/WlT[n][k] bf16 (transposed, truncation split) ----------------

__global__ __launch_bounds__(256) void k_wsplit(const float* __restrict__ W,
                                                unsigned short* __restrict__ WhT,
                                                unsigned short* __restrict__ WlT) {
    int idx = blockIdx.x * 256 + threadIdx.x;   // layer*16384 + k*128 + n
    if (idx >= N_CONV * DIM * DIM) return;
    int layer = idx >> 14;
    int rem = idx & 16383;
    int k = rem >> 7;
    int n = rem & 127;
    float f = W[idx];
    unsigned int u = __float_as_uint(f);
    unsigned int h = u & 0xFFFF0000u;
    float lo = f - __uint_as_float(h);
    int dst = (layer << 14) | (n << 7) | k;
    WhT[dst] = (unsigned short)(h >> 16);
    WlT[dst] = (unsigned short)(__float_as_uint(lo) >> 16);
}

// ---------------- GEMM via MFMA bf16x3: C[N,128] = A[N,128] @ W[128,128] ----------------
// block: 256 thr = 4 waves x 64 rows = 256 rows. Whole WhT/WlT in 64KB LDS (XOR-swizzled).
// frags: A row=l&15, k=8*(l>>4)+j (k-contiguous, m97-verified); D col=l&15, row=(l>>4)*4+r.

__global__ __launch_bounds__(256, 2) void k_gemm_mfma(const float* __restrict__ Ain,
                                                      const unsigned short* __restrict__ WhT,
                                                      const unsigned short* __restrict__ WlT,
                                                      float* __restrict__ Cout) {
    __shared__ unsigned short WL[2 * DIM * DIM];   // 64 KB: [h|l][n][k] swizzled

    int t = threadIdx.x;
    // stage both halves; 2048 uint4 per half, 8 iters x 256 thr
#pragma unroll
    for (int it = 0; it < 8; ++it) {
        int idx = it * 256 + t;          // uint4 index (8 bf16 each)
        int n = idx >> 4;
        int kc = idx & 15;
        int byte = n * 256 + kc * 16;
        int swz = byte ^ ((n & 7) << 4);
        *(uint4*)((char*)WL + swz) = ((const uint4*)WhT)[idx];
        *(uint4*)((char*)WL + 32768 + swz) = ((const uint4*)WlT)[idx];
    }
    __syncthreads();

    int w = t >> 6;
    int l = t & 63;
    int lr = l & 15;     // A-row-in-tile / D-col
    int lk = l >> 4;     // k-group
    int row_base = blockIdx.x * 256 + w * 64;

    f32x4 acc[4][8];
#pragma unroll
    for (int m = 0; m < 4; ++m)
#pragma unroll
        for (int nt = 0; nt < 8; ++nt) acc[m][nt] = (f32x4)0.0f;

    const char* WLB = (const char*)WL;
    int wswz = (lr & 7) << 4;    // (n&7)<<4 with n = nt*16+lr

#pragma unroll 1
    for (int kt = 0; kt < 4; ++kt) {
        // load + split A fragments for 4 m-tiles
        s16x8 ah[4], al[4];
#pragma unroll
        for (int m = 0; m < 4; ++m) {
            int row = row_base + m * 16 + lr;
            int rc = row < N_NODES ? row : N_NODES - 1;
            const float* ap = Ain + (size_t)rc * DIM + kt * 32 + lk * 8;
            float4 f0 = *(const float4*)ap;
            float4 f1 = *(const float4*)(ap + 4);
            float fs[8] = {f0.x, f0.y, f0.z, f0.w, f1.x, f1.y, f1.z, f1.w};
            union { int i[4]; s16x8 v; } H, L;
#pragma unroll
            for (int d = 0; d < 4; ++d) {
                float a0 = fs[2 * d], a1 = fs[2 * d + 1];
                unsigned int u0 = __float_as_uint(a0), u1 = __float_as_uint(a1);
                unsigned int h0 = u0 & 0xFFFF0000u, h1 = u1 & 0xFFFF0000u;
                float lo0 = a0 - __uint_as_float(h0);
                float lo1 = a1 - __uint_as_float(h1);
                H.i[d] = (int)(h1 | (h0 >> 16));
                L.i[d] = (int)((__float_as_uint(lo1) & 0xFFFF0000u) | (__float_as_uint(lo0) >> 16));
            }
            ah[m] = H.v;
            al[m] = L.v;
        }
#pragma unroll
        for (int nt = 0; nt < 8; ++nt) {
            int nbyte = ((nt * 16 + lr) * 256 + kt * 64 + lk * 16) ^ wswz;
            s16x8 wh = *(const s16x8*)(WLB + nbyte);
            s16x8 wl = *(const s16x8*)(WLB + 32768 + nbyte);
#pragma unroll
            for (int m = 0; m < 4; ++m) {
                acc[m][nt] = __builtin_amdgcn_mfma_f32_16x16x32_bf16(ah[m], wh, acc[m][nt], 0, 0, 0);
                acc[m][nt] = __builtin_amdgcn_mfma_f32_16x16x32_bf16(ah[m], wl, acc[m][nt], 0, 0, 0);
                acc[m][nt] = __builtin_amdgcn_mfma_f32_16x16x32_bf16(al[m], wh, acc[m][nt], 0, 0, 0);
            }
        }
    }

#pragma unroll
    for (int m = 0; m < 4; ++m)
#pragma unroll
        for (int nt = 0; nt < 8; ++nt)
#pragma unroll
            for (int r = 0; r < 4; ++r) {
                int row = row_base + m * 16 + lk * 4 + r;
                if (row < N_NODES) Cout[(size_t)row * DIM + nt * 16 + lr] = acc[m][nt][r];
            }
}

// ---------------- pull aggregation + bias + relu (fused) ----------------

__global__ __launch_bounds__(256) void k_gather(const float4* __restrict__ B4,
                                                const int* __restrict__ rp,
                                                const int* __restrict__ src_csr,
                                                const float* __restrict__ norm_csr,
                                                const float* __restrict__ dis,
                                                const float* __restrict__ bias,
                                                float4* __restrict__ A4) {
    int t = threadIdx.x;
    int n = blockIdx.x * 8 + (t >> 5);      // 100000 / 8 = 12500 blocks exact
    int lane = t & 31;

    float dn = dis[n];
    float self_nrm = dn * dn;
    float4 v = B4[n * 32 + lane];
    float4 acc = make_float4(v.x * self_nrm, v.y * self_nrm, v.z * self_nrm, v.w * self_nrm);

    int beg = rp[n], end = rp[n + 1];
    int e = beg;
    for (; e + 1 < end; e += 2) {
        int s0 = src_csr[e];
        int s1 = src_csr[e + 1];
        float nm0 = norm_csr[e];
        float nm1 = norm_csr[e + 1];
        float4 u0 = B4[s0 * 32 + lane];
        float4 u1 = B4[s1 * 32 + lane];
        acc.x += u0.x * nm0; acc.y += u0.y * nm0; acc.z += u0.z * nm0; acc.w += u0.w * nm0;
        acc.x += u1.x * nm1; acc.y += u1.y * nm1; acc.z += u1.z * nm1; acc.w += u1.w * nm1;
    }
    if (e < end) {
        int s0 = src_csr[e];
        float nm0 = norm_csr[e];
        float4 u0 = B4[s0 * 32 + lane];
        acc.x += u0.x * nm0; acc.y += u0.y * nm0; acc.z += u0.z * nm0; acc.w += u0.w * nm0;
    }

    float4 b = ((const float4*)bias)[lane];
    acc.x = fmaxf(acc.x + b.x, 0.f);
    acc.y = fmaxf(acc.y + b.y, 0.f);
    acc.z = fmaxf(acc.z + b.z, 0.f);
    acc.w = fmaxf(acc.w + b.w, 0.f);
    A4[n * 32 + lane] = acc;
}

// ---------------- segmented pooling ----------------

__global__ __launch_bounds__(256) void k_pool_seg(const float4* __restrict__ A4,
                                                  const int* __restrict__ grp,
                                                  float4* __restrict__ means4) {
    __shared__ float4 s[256];
    int g = blockIdx.x;
    int t = threadIdx.x;
    int lane = t & 31;
    int slot = t >> 5;
    int beg = grp[g], end = grp[g + 1];

    float4 acc = make_float4(0.f, 0.f, 0.f, 0.f);
    for (int n = beg + slot; n < end; n += 8) {
        float4 v = A4[(size_t)n * 32 + lane];
        acc.x += v.x; acc.y += v.y; acc.z += v.z; acc.w += v.w;
    }
    s[t] = acc;
    __syncthreads();
    if (t < 32) {
        float4 a = s[t];
#pragma unroll
        for (int i = 1; i < 8; ++i) {
            float4 b = s[t + i * 32];
            a.x += b.x; a.y += b.y; a.z += b.z; a.w += b.w;
        }
        float inv = (end > beg) ? 1.0f / (float)(end - beg) : 0.0f;
        means4[g * 32 + t] = make_float4(a.x * inv, a.y * inv, a.z * inv, a.w * inv);
    }
}

// ---------------- MLP head ----------------

__global__ __launch_bounds__(256) void k_mlp(const float* __restrict__ means,
                                             const float* __restrict__ w1,
                                             const float* __restrict__ b1,
                                             const float* __restrict__ w2,
                                             const float* __restrict__ b2,
                                             float* __restrict__ out) {
    __shared__ float m[DIM];
    __shared__ float red[HIDDEN];
    int g = blockIdx.x;
    int t = threadIdx.x;
    if (t < DIM) m[t] = means[g * DIM + t];
    __syncthreads();
    float h = b1[t];
    for (int c = 0; c < DIM; ++c) h += m[c] * w1[c * HIDDEN + t];
    red[t] = fmaxf(h, 0.f) * w2[t];
    __syncthreads();
    for (int s = HIDDEN / 2; s > 0; s >>= 1) {
        if (t < s) red[t] += red[t + s];
        __syncthreads();
    }
    if (t == 0) out[g] = red[0] + b2[0];
}

// ---------------- launch ----------------

extern "C" void kernel_launch(void* const* d_in, const int* in_sizes, int n_in,
                              void* d_out, int out_size, void* d_ws, size_t ws_size,
                              hipStream_t stream) {
    const float* x      = (const float*)d_in[0];
    const float* conv_w = (const float*)d_in[1];
    const float* conv_b = (const float*)d_in[2];
    const float* w1     = (const float*)d_in[3];
    const float* b1     = (const float*)d_in[4];
    const float* w2     = (const float*)d_in[5];
    const float* b2     = (const float*)d_in[6];
    const int*   ei     = (const int*)d_in[7];
    const int*   batch  = (const int*)d_in[8];
    float* out = (float*)d_out;

    char* ws = (char*)d_ws;
    size_t off = 0;
    auto alloc = [&](size_t bytes) {
        char* p = ws + off;
        off += (bytes + 255) & ~(size_t)255;
        return p;
    };
    float* A        = (float*)alloc((size_t)N_NODES * DIM * 4);   // 51.2 MB
    float* Bb       = (float*)alloc((size_t)N_NODES * DIM * 4);   // 51.2 MB
    int*   cnt      = (int*)alloc((size_t)N_NODES * 4);
    float* dis      = (float*)alloc((size_t)N_NODES * 4);
    int*   rp       = (int*)alloc((size_t)(N_NODES + 1) * 4);
    int*   part     = (int*)alloc((size_t)NB_SCAN * 4);
    int*   src_csr  = (int*)alloc((size_t)N_EDGES * 4);
    float* norm_csr = (float*)alloc((size_t)N_EDGES * 4);
    int*   grp      = (int*)alloc((size_t)(N_GRAPHS + 1) * 4);
    float* means    = (float*)alloc((size_t)N_GRAPHS * DIM * 4);
    unsigned short* WhT = (unsigned short*)alloc((size_t)N_CONV * DIM * DIM * 2);
    unsigned short* WlT = (unsigned short*)alloc((size_t)N_CONV * DIM * DIM * 2);
    (void)ws_size; (void)in_sizes; (void)n_in; (void)out_size;

    // --- CSR build + W split (once per call) ---
    hipMemsetAsync(cnt, 0, (size_t)N_NODES * 4, stream);
    k_hist<<<(N_EDGES + 255) / 256, 256, 0, stream>>>(ei, cnt);
    k_dis<<<(N_NODES + 255) / 256, 256, 0, stream>>>(cnt, dis);
    k_scan1<<<NB_SCAN, 256, 0, stream>>>(cnt, rp, part);
    k_scan2<<<1, 512, 0, stream>>>(part);
    k_scan3<<<NB_SCAN, 256, 0, stream>>>(rp, part);
    hipMemsetAsync(cnt, 0, (size_t)N_NODES * 4, stream);
    k_fill<<<(N_EDGES + 255) / 256, 256, 0, stream>>>(ei, rp, dis, cnt, src_csr, norm_csr);
    k_grp<<<(N_GRAPHS + 256) / 256, 256, 0, stream>>>(batch, grp);
    k_wsplit<<<(N_CONV * DIM * DIM) / 256, 256, 0, stream>>>(conv_w, WhT, WlT);

    // --- conv layers ---
    const float* cur = x;
    for (int L = 0; L < N_CONV; ++L) {
        k_gemm_mfma<<<(N_NODES + 255) / 256, 256, 0, stream>>>(
            cur, WhT + L * DIM * DIM, WlT + L * DIM * DIM, Bb);
        k_gather<<<N_NODES / 8, 256, 0, stream>>>((const float4*)Bb, rp, src_csr, norm_csr,
                                                  dis, conv_b + L * DIM, (float4*)A);
        cur = A;
    }

    // --- pool + MLP ---
    k_pool_seg<<<N_GRAPHS, 256, 0, stream>>>((const float4*)A, grp, (float4*)means);
    k_mlp<<<N_GRAPHS, 256, 0, stream>>>(means, w1, b1, w2, b2, out);
}